// Round 5
// baseline (567.407 us; speedup 1.0000x reference)
//
#include <hip/hip_runtime.h>
#include <math.h>

#define PDIM 8
#define BSZ 256
#define CEEG 22
#define TLEN 1000
#define KW 12
#define C2 96
#define TOUT 989
#define TSTR 992          // padded h2 row stride (16B-aligned float4 stores)
#define NSWEEP 7
#define NTILE 11          // k3 tiles of 96 outputs
#define NPART (128*NTILE) // k3 stat partial groups

// ---- workspace layout (in floats) ----
#define OFF_H1   ((size_t)0)
#define SZ_H1    ((size_t)BSZ*CEEG*TLEN)
#define OFF_H2   (OFF_H1 + SZ_H1)
#define SZ_H2    ((size_t)BSZ*C2*TSTR)
#define OFF_S    (OFF_H2 + SZ_H2)
#define SZ_S     ((size_t)BSZ*3*1024)
#define OFF_QQT  (OFF_S + SZ_S)
#define SZ_QQT   ((size_t)BSZ*3*256)
#define OFF_KKT  (OFF_QQT + SZ_QQT)
#define OFF_VP   (OFF_KKT + SZ_QQT)
#define SZ_VP    ((size_t)BSZ*256)
#define OFF_P1   (OFF_VP + SZ_VP)
#define SZ_P1    ((size_t)BSZ*44)
#define OFF_P2   (OFF_P1 + SZ_P1)
#define SZ_P2    ((size_t)NPART*192)
#define OFF_BN1  (OFF_P2 + SZ_P2)
#define OFF_BN2  (OFF_BN1 + (size_t)64)

// ================= K1: conv1 (22ch spatial filter) + BN1 partial stats ==========
__global__ __launch_bounds__(256) void k1_conv1(const float* __restrict__ x,
        const float* __restrict__ w1, float* __restrict__ h1,
        float* __restrict__ part1) {
    __shared__ float sw[CEEG*CEEG];       // [o][c]
    __shared__ float red[4][44];
    int b = blockIdx.x;
    int tid = threadIdx.x;
    for (int i = tid; i < CEEG*CEEG; i += 256) sw[i] = w1[i];
    __syncthreads();
    float sum[CEEG], sumsq[CEEG];
    #pragma unroll
    for (int o = 0; o < CEEG; ++o) { sum[o] = 0.f; sumsq[o] = 0.f; }
    const float* xb = x + (size_t)b*CEEG*TLEN;
    float* hb = h1 + (size_t)b*CEEG*TLEN;
    for (int it = 0; it < 4; ++it) {
        int t = it*256 + tid;
        if (t < TLEN) {
            float acc[CEEG];
            #pragma unroll
            for (int o = 0; o < CEEG; ++o) acc[o] = 0.f;
            #pragma unroll 2
            for (int c = 0; c < CEEG; ++c) {
                float xv = xb[c*TLEN + t];
                #pragma unroll
                for (int o = 0; o < CEEG; ++o) acc[o] = fmaf(xv, sw[o*CEEG + c], acc[o]);
            }
            #pragma unroll
            for (int o = 0; o < CEEG; ++o) {
                hb[o*TLEN + t] = acc[o];
                sum[o]  += acc[o];
                sumsq[o] += acc[o]*acc[o];
            }
        }
    }
    int lane = tid & 63, wv = tid >> 6;
    #pragma unroll
    for (int o = 0; o < CEEG; ++o) {
        float s = sum[o], s2 = sumsq[o];
        for (int off = 32; off > 0; off >>= 1) {
            s  += __shfl_down(s,  off, 64);
            s2 += __shfl_down(s2, off, 64);
        }
        if (lane == 0) { red[wv][o] = s; red[wv][CEEG + o] = s2; }
    }
    __syncthreads();
    if (tid < 44) {
        part1[(size_t)b*44 + tid] = red[0][tid] + red[1][tid] + red[2][tid] + red[3][tid];
    }
}

// ================= K2: finalize BN1 params (1 block / channel) ==========
__global__ __launch_bounds__(64) void k2_bn1(const float* __restrict__ part1,
        const float* __restrict__ g, const float* __restrict__ bta, float* __restrict__ p1) {
    int c = blockIdx.x, t = threadIdx.x;
    float s = 0.f, s2 = 0.f;
    for (int blk = t; blk < BSZ; blk += 64) {
        s  += part1[(size_t)blk*44 + c];
        s2 += part1[(size_t)blk*44 + CEEG + c];
    }
    for (int off = 32; off > 0; off >>= 1) {
        s  += __shfl_down(s,  off, 64);
        s2 += __shfl_down(s2, off, 64);
    }
    if (t == 0) {
        double N = (double)BSZ * (double)TLEN;
        double mu = (double)s / N, var = (double)s2 / N - mu*mu;
        double scale = (double)g[c] / sqrt(var + 1e-5);
        p1[c] = (float)scale;
        p1[CEEG + c] = (float)((double)bta[c] - mu*scale);
    }
}

// ================= K3 v3: conv2, 2 batches/block, 3o x 12t x 2b per thread ====
__global__ __launch_bounds__(256) void k3_conv2(const float* __restrict__ h1,
        const float* __restrict__ w2, const float* __restrict__ p1,
        float* __restrict__ h2, float* __restrict__ part2) {
    __shared__ float sin_[2][CEEG][112];    // staged input (BN1+ELU), 2 batches
    __shared__ float swt[2][C2*14];         // double-buffered weights [o][14]
    __shared__ float rStat[C2][8];          // per-(o, wave) partial sums {s,s2}x4
    int bp = blockIdx.x;                    // batch pair: batches 2bp, 2bp+1
    int tile = blockIdx.y;                  // 0..10
    int t0 = tile * 96;
    int tid = threadIdx.x;
    int og = tid & 31;                      // o base = 3*og
    int tg = tid >> 5;                      // 0..7, t base = 12*tg
    int ob = 3*og;

    // stage both input windows with BN1+ELU; zero where t >= TLEN
    for (int i = tid; i < 2*CEEG*112; i += 256) {
        int bb = i / (CEEG*112);
        int rem = i - bb*(CEEG*112);
        int c = rem / 112, tt = rem - c*112;
        float v = 0.f;
        int t = t0 + tt;
        if (t < TLEN) {
            const float* hb = h1 + (size_t)(2*bp + bb)*CEEG*TLEN;
            float z = fmaf(hb[c*TLEN + t], p1[c], p1[CEEG + c]);
            v = z > 0.f ? z : expm1f(z);
        }
        sin_[bb][c][tt] = v;
    }
    // stage weights for c=0 into buf 0
    for (int i = tid; i < C2*KW; i += 256) {
        int o = i / KW, k = i - o*KW;
        swt[0][o*14 + k] = w2[o*264 + k];   // c=0
    }
    __syncthreads();

    float acc[2][3][12];
    #pragma unroll
    for (int bb = 0; bb < 2; ++bb)
        #pragma unroll
        for (int j = 0; j < 3; ++j)
            #pragma unroll
            for (int i = 0; i < 12; ++i) acc[bb][j][i] = 0.f;

    for (int c = 0; c < CEEG; ++c) {
        int buf = c & 1;
        // prefetch weights for c+1 into other buffer
        if (c + 1 < CEEG) {
            int cn = c + 1;
            for (int i = tid; i < C2*KW; i += 256) {
                int o = i / KW, k = i - o*KW;
                swt[buf ^ 1][o*14 + k] = w2[o*264 + cn*12 + k];
            }
        }
        // this thread's weights (float2, 2-way bank alias = free)
        float aw[3][12];
        #pragma unroll
        for (int j = 0; j < 3; ++j) {
            const float2* wr = (const float2*)&swt[buf][(ob + j)*14];
            #pragma unroll
            for (int h = 0; h < 6; ++h) {
                float2 wv2 = wr[h];
                aw[j][2*h] = wv2.x; aw[j][2*h + 1] = wv2.y;
            }
        }
        // batch 0 then batch 1, reusing bw registers
        #pragma unroll
        for (int bb = 0; bb < 2; ++bb) {
            float bw[24];
            const float4* br = (const float4*)&sin_[bb][c][12*tg];
            #pragma unroll
            for (int h = 0; h < 6; ++h) {
                float4 bv = br[h];
                bw[4*h] = bv.x; bw[4*h+1] = bv.y; bw[4*h+2] = bv.z; bw[4*h+3] = bv.w;
            }
            #pragma unroll
            for (int k = 0; k < KW; ++k) {
                #pragma unroll
                for (int j = 0; j < 3; ++j) {
                    float a = aw[j][k];
                    #pragma unroll
                    for (int i = 0; i < 12; ++i)
                        acc[bb][j][i] = fmaf(a, bw[i + k], acc[bb][j][i]);
                }
            }
        }
        __syncthreads();
    }

    // stores + BN2 partial stats (summed over both batches)
    int tbase = t0 + 12*tg;
    float sj[3], s2j[3];
    #pragma unroll
    for (int j = 0; j < 3; ++j) { sj[j] = 0.f; s2j[j] = 0.f; }
    #pragma unroll
    for (int bb = 0; bb < 2; ++bb) {
        float* h2b = h2 + (size_t)(2*bp + bb)*C2*TSTR;
        #pragma unroll
        for (int j = 0; j < 3; ++j) {
            int o = ob + j;
            if (tbase + 11 < TOUT) {
                float* dst = &h2b[(size_t)o*TSTR + tbase];
                #pragma unroll
                for (int h = 0; h < 3; ++h) {
                    *(float4*)&dst[4*h] = make_float4(acc[bb][j][4*h], acc[bb][j][4*h+1],
                                                      acc[bb][j][4*h+2], acc[bb][j][4*h+3]);
                    #pragma unroll
                    for (int u = 0; u < 4; ++u) {
                        float v = acc[bb][j][4*h + u];
                        sj[j] += v; s2j[j] += v*v;
                    }
                }
            } else {
                #pragma unroll
                for (int i = 0; i < 12; ++i) {
                    int t = tbase + i;
                    if (t < TOUT) {
                        float v = acc[bb][j][i];
                        h2b[(size_t)o*TSTR + t] = v;
                        sj[j] += v; s2j[j] += v*v;
                    }
                }
            }
        }
    }
    // reduce across tg: partner lane is lane^32 (same og, other tg in wave)
    int wv = tid >> 6;
    #pragma unroll
    for (int j = 0; j < 3; ++j) {
        sj[j]  += __shfl_xor(sj[j],  32, 64);
        s2j[j] += __shfl_xor(s2j[j], 32, 64);
        if ((tid & 63) < 32) {
            rStat[ob + j][2*wv]     = sj[j];
            rStat[ob + j][2*wv + 1] = s2j[j];
        }
    }
    __syncthreads();
    if (tid < C2) {
        float s = rStat[tid][0] + rStat[tid][2] + rStat[tid][4] + rStat[tid][6];
        float s2 = rStat[tid][1] + rStat[tid][3] + rStat[tid][5] + rStat[tid][7];
        float* pb = part2 + ((size_t)bp*NTILE + tile)*192;
        pb[tid] = s; pb[96 + tid] = s2;
    }
}

// ================= K4: finalize BN2 params (1 block / channel) ==========
__global__ __launch_bounds__(256) void k4_bn2(const float* __restrict__ part2,
        const float* __restrict__ g, const float* __restrict__ bta, float* __restrict__ p2) {
    __shared__ float rs[4], rs2[4];
    int q = blockIdx.x, t = threadIdx.x;
    float s = 0.f, s2 = 0.f;
    for (int blk = t; blk < NPART; blk += 256) {
        s  += part2[(size_t)blk*192 + q];
        s2 += part2[(size_t)blk*192 + 96 + q];
    }
    for (int off = 32; off > 0; off >>= 1) {
        s  += __shfl_down(s,  off, 64);
        s2 += __shfl_down(s2, off, 64);
    }
    int lane = t & 63, wv = t >> 6;
    if (lane == 0) { rs[wv] = s; rs2[wv] = s2; }
    __syncthreads();
    if (t == 0) {
        double S  = (double)rs[0]  + rs[1]  + rs[2]  + rs[3];
        double S2 = (double)rs2[0] + rs2[1] + rs2[2] + rs2[3];
        double N = (double)BSZ * (double)TOUT;
        double mu = S / N, var = S2 / N - mu*mu;
        double scale = (double)g[q] / sqrt(var + 1e-5);
        p2[q] = (float)scale;
        p2[C2 + q] = (float)((double)bta[q] - mu*scale);
    }
}

// ================= K5: BN2+ELU fused Gram matrices S[b][m] = X X^T ==========
__global__ __launch_bounds__(256) void k5_gram(const float* __restrict__ h2,
        const float* __restrict__ p2, float* __restrict__ S) {
    __shared__ float sx[32][68];
    int bm = blockIdx.x;
    int b = bm / 3, m = bm % 3;
    int tid = threadIdx.x;
    int r0 = (tid >> 4) * 2;
    int c0 = (tid & 15) * 2;
    float a00 = 0.f, a01 = 0.f, a10 = 0.f, a11 = 0.f;
    const float* hb = h2 + ((size_t)b*C2 + m*32)*TSTR;
    int row = tid >> 3;
    int ts  = (tid & 7) * 8;
    float sc = p2[m*32 + row], sh = p2[C2 + m*32 + row];
    for (int t0 = 0; t0 < TOUT; t0 += 64) {
        __syncthreads();
        #pragma unroll
        for (int j = 0; j < 8; ++j) {
            int t = t0 + ts + j;
            float v = 0.f;
            if (t < TOUT) {
                float z = fmaf(hb[(size_t)row*TSTR + t], sc, sh);
                v = z > 0.f ? z : expm1f(z);
            }
            sx[row][ts + j] = v;
        }
        __syncthreads();
        #pragma unroll
        for (int tt = 0; tt < 64; tt += 4) {
            float4 va0 = *(const float4*)&sx[r0][tt];
            float4 va1 = *(const float4*)&sx[r0+1][tt];
            float4 vb0 = *(const float4*)&sx[c0][tt];
            float4 vb1 = *(const float4*)&sx[c0+1][tt];
            a00 = fmaf(va0.x, vb0.x, fmaf(va0.y, vb0.y, fmaf(va0.z, vb0.z, fmaf(va0.w, vb0.w, a00))));
            a01 = fmaf(va0.x, vb1.x, fmaf(va0.y, vb1.y, fmaf(va0.z, vb1.z, fmaf(va0.w, vb1.w, a01))));
            a10 = fmaf(va1.x, vb0.x, fmaf(va1.y, vb0.y, fmaf(va1.z, vb0.z, fmaf(va1.w, vb0.w, a10))));
            a11 = fmaf(va1.x, vb1.x, fmaf(va1.y, vb1.y, fmaf(va1.z, vb1.z, fmaf(va1.w, vb1.w, a11))));
        }
    }
    float* Sb = S + (size_t)bm*1024;
    Sb[r0*32 + c0]       = a00;
    Sb[r0*32 + c0 + 1]   = a01;
    Sb[(r0+1)*32 + c0]   = a10;
    Sb[(r0+1)*32 + c0+1] = a11;
}

// ================= K6: parallel Jacobi eigh: 256 thr/matrix, b64 V, f2 cs ======
__device__ __forceinline__ void pair_of(int r, int k, int& p, int& q) {
    if (k == 0) { p = r; q = 31; }
    else {
        int a = (r + k) % 31;
        int b2 = (r - k + 31) % 31;
        p = min(a, b2); q = max(a, b2);
    }
}

__global__ __launch_bounds__(256) void k6_eig(const float* __restrict__ S,
        const float* __restrict__ wq, const float* __restrict__ wk, const float* __restrict__ wv,
        float* __restrict__ QQt, float* __restrict__ KKt, float* __restrict__ Vp) {
    __shared__ float A[32][33];
    __shared__ float Vt[32][34];            // V transposed: Vt[col][row], even stride
    __shared__ float2 cs2[16];
    __shared__ float sW[3][512];
    __shared__ unsigned int ptab[31*16];
    __shared__ float Up[32][9];
    __shared__ float Aw[16][9];
    __shared__ float G[8][9];
    __shared__ float Lm[8][9];
    __shared__ float Mm[16][9];
    __shared__ float lam[32];
    int bm = blockIdx.x, b = bm / 3, m = bm % 3;
    int tid = threadIdx.x;
    const float* Sb = S + (size_t)bm*1024;
    for (int i = tid; i < 1024; i += 256) {
        int r_ = i >> 5, c_ = i & 31;
        A[r_][c_] = Sb[i];
        Vt[r_][c_] = (r_ == c_) ? 1.f : 0.f;
    }
    for (int i = tid; i < 512; i += 256) {
        sW[0][i] = wq[i]; sW[1][i] = wk[i]; sW[2][i] = wv[i];
    }
    for (int i = tid; i < 31*16; i += 256) {
        int r_ = i >> 4, k_ = i & 15;
        int p, q; pair_of(r_, k_, p, q);
        ptab[i] = (unsigned)p | ((unsigned)q << 16);
    }
    __syncthreads();

    int kk_ = tid >> 4, ll_ = tid & 15;
    int i0 = kk_ * 2;
    for (int sweep = 0; sweep < NSWEEP; ++sweep) {
        for (int r = 0; r < 31; ++r) {
            if (tid < 16) {
                unsigned pq = ptab[(r << 4) + tid];
                int p = pq & 0xffff, q = pq >> 16;
                float app = A[p][p], aqq = A[q][q], apq = A[p][q];
                float c = 1.f, s = 0.f;
                if (apq != 0.f) {
                    float tau = (aqq - app) / (2.f * apq);
                    float tt = (tau >= 0.f ? 1.f : -1.f) / (fabsf(tau) + sqrtf(1.f + tau*tau));
                    c = 1.f / sqrtf(1.f + tt*tt);
                    s = tt * c;
                    if (!(c == c) || !(s == s)) { c = 1.f; s = 0.f; }
                }
                cs2[tid] = make_float2(c, s);
            }
            __syncthreads();
            {
                unsigned pqk = ptab[(r << 4) + kk_];
                unsigned pql = ptab[(r << 4) + ll_];
                int p = pqk & 0xffff, q = pqk >> 16;
                int rr = pql & 0xffff, ss = pql >> 16;
                float2 ck2 = cs2[kk_], cl2 = cs2[ll_];
                float ck = ck2.x, sk = ck2.y, cl = cl2.x, sl = cl2.y;
                float apr = A[p][rr], aps = A[p][ss], aqr = A[q][rr], aqs = A[q][ss];
                float tpr = ck*apr - sk*aqr;
                float tqr = sk*apr + ck*aqr;
                float tps = ck*aps - sk*aqs;
                float tqs = sk*aps + ck*aqs;
                A[p][rr] = cl*tpr - sl*tps;
                A[p][ss] = sl*tpr + cl*tps;
                A[q][rr] = cl*tqr - sl*tqs;
                A[q][ss] = sl*tqr + cl*tqs;
                // V update (transposed layout): cols rr,ss of V = rows of Vt
                float2 vr = *(const float2*)&Vt[rr][i0];
                float2 vs = *(const float2*)&Vt[ss][i0];
                float2 nvr, nvs;
                nvr.x = cl*vr.x - sl*vs.x;
                nvr.y = cl*vr.y - sl*vs.y;
                nvs.x = sl*vr.x + cl*vs.x;
                nvs.y = sl*vr.y + cl*vs.y;
                *(float2*)&Vt[rr][i0] = nvr;
                *(float2*)&Vt[ss][i0] = nvs;
            }
            __syncthreads();
        }
    }

    // top-8 eigenvalue selection (descending) -> Up (Up[row][rank] = Vt[col][row])
    if (tid < 32) lam[tid] = A[tid][tid];
    __syncthreads();
    if (tid < 32) {
        float lj = lam[tid];
        int rank = 0;
        #pragma unroll
        for (int i = 0; i < 32; ++i) {
            float li = lam[i];
            rank += (li > lj) || (li == lj && i < tid);
        }
        if (rank < PDIM) {
            #pragma unroll
            for (int i = 0; i < 32; ++i) Up[i][rank] = Vt[tid][i];
        }
    }
    __syncthreads();

    // projections: P = A (A^T A)^{-1} A^T for A = W * Up  (== qr(A).Q @ Q^T)
    for (int widx = 0; widx < 3; ++widx) {
        if (widx == 2 && m != 2) break;   // V-projection only needed for m==2
        const float* W = sW[widx];
        if (tid < 128) {
            int o = tid >> 3, pp = tid & 7;
            float s = 0.f;
            #pragma unroll
            for (int i = 0; i < 32; ++i) s = fmaf(W[o*32 + i], Up[i][pp], s);
            Aw[o][pp] = s;
        }
        __syncthreads();
        if (tid < 64) {
            int xx = tid >> 3, yy = tid & 7;
            float s = 0.f;
            #pragma unroll
            for (int o = 0; o < 16; ++o) s = fmaf(Aw[o][xx], Aw[o][yy], s);
            G[xx][yy] = s;
        }
        __syncthreads();
        if (tid == 0) {
            float Lr[8][8];
            #pragma unroll
            for (int jj = 0; jj < 8; ++jj) {
                float d = G[jj][jj];
                #pragma unroll
                for (int kk = 0; kk < 8; ++kk) if (kk < jj) d -= Lr[jj][kk]*Lr[jj][kk];
                d = sqrtf(fmaxf(d, 1e-30f));
                float inv = 1.f / d;
                Lr[jj][jj] = d;
                Lm[jj][jj] = inv;     // store INVERSE of diagonal
                #pragma unroll
                for (int ii = 0; ii < 8; ++ii) if (ii > jj) {
                    float v = G[ii][jj];
                    #pragma unroll
                    for (int kk = 0; kk < 8; ++kk) if (kk < jj) v -= Lr[ii][kk]*Lr[jj][kk];
                    v *= inv;
                    Lr[ii][jj] = v;
                    Lm[ii][jj] = v;
                }
            }
        }
        __syncthreads();
        if (tid < 16) {
            int o = tid;
            float a[8], mv[8];
            #pragma unroll
            for (int pp = 0; pp < 8; ++pp) a[pp] = Aw[o][pp];
            #pragma unroll
            for (int jj = 0; jj < 8; ++jj) {
                float v = a[jj];
                #pragma unroll
                for (int kk = 0; kk < 8; ++kk) if (kk < jj) v -= Lm[jj][kk]*mv[kk];
                mv[jj] = v * Lm[jj][jj];
            }
            #pragma unroll
            for (int pp = 0; pp < 8; ++pp) Mm[o][pp] = mv[pp];
        }
        __syncthreads();
        {
            int d = tid >> 4, e = tid & 15;
            float s = 0.f;
            #pragma unroll
            for (int pp = 0; pp < 8; ++pp) s = fmaf(Mm[d][pp], Mm[e][pp], s);
            float* dst = (widx == 0) ? (QQt + (size_t)bm*256)
                       : (widx == 1) ? (KKt + (size_t)bm*256)
                       : (Vp + (size_t)b*256);
            dst[d*16 + e] = s;
        }
        __syncthreads();
    }
}

// ================= K7: attention scores + softmax(i=2) + output linear ==========
__global__ __launch_bounds__(64) void k7_out(const float* __restrict__ QQt,
        const float* __restrict__ KKt, const float* __restrict__ Vp,
        const float* __restrict__ lw, const float* __restrict__ lb,
        float* __restrict__ out) {
    __shared__ float sQ[3][256], sK[3][256], sVp[256], ssc[9], wj[3];
    int b = blockIdx.x, tid = threadIdx.x;
    for (int i = tid; i < 768; i += 64) {
        sQ[i >> 8][i & 255] = QQt[(size_t)b*768 + i];
        sK[i >> 8][i & 255] = KKt[(size_t)b*768 + i];
    }
    for (int i = tid; i < 256; i += 64) sVp[i] = Vp[(size_t)b*256 + i];
    __syncthreads();
    for (int pair = 0; pair < 9; ++pair) {
        int i = pair / 3, j = pair % 3;
        const float* Qj = sQ[j];
        const float* Ki = sK[i];
        float accp = 0.f;
        #pragma unroll
        for (int it = 0; it < 4; ++it) {
            int e = tid + 64*it;
            int d = e >> 4, ee = e & 15;
            float y = 0.f;
            #pragma unroll
            for (int f = 0; f < 16; ++f) {
                float dv = Qj[d*16 + f] - Ki[d*16 + f];
                float ev = Qj[ee*16 + f] - Ki[ee*16 + f];
                y = fmaf(dv, ev, y);
            }
            accp += y*y;
        }
        for (int off = 32; off > 0; off >>= 1) accp += __shfl_down(accp, off, 64);
        if (tid == 0) {
            float E = sqrtf(accp);
            ssc[pair] = 1.f / (1.f + log1pf(E));
        }
        __syncthreads();
    }
    if (tid < 3) {
        int j = tid;
        float e0 = expf(ssc[0*3 + j]), e1 = expf(ssc[1*3 + j]), e2 = expf(ssc[2*3 + j]);
        wj[j] = e2 / (e0 + e1 + e2);
    }
    __syncthreads();
    int o = tid >> 4, g = tid & 15;
    float part = 0.f;
    #pragma unroll
    for (int t = 0; t < 16; ++t) {
        int de = g*16 + t;
        float vv = sVp[de];
        float l0 = lw[o*768 + de];
        float l1 = lw[o*768 + 256 + de];
        float l2 = lw[o*768 + 512 + de];
        part = fmaf(vv, fmaf(wj[0], l0, fmaf(wj[1], l1, wj[2]*l2)), part);
    }
    for (int off = 8; off > 0; off >>= 1) part += __shfl_down(part, off, 16);
    if (g == 0) out[b*4 + o] = part + lb[o];
}

// ================= launch ==========
extern "C" void kernel_launch(void* const* d_in, const int* in_sizes, int n_in,
                              void* d_out, int out_size, void* d_ws, size_t ws_size,
                              hipStream_t stream) {
    const float* x  = (const float*)d_in[0];
    const float* w1 = (const float*)d_in[1];
    // d_in[2] conv1_b: cancels exactly in batch-norm (mean subtraction) -> unused
    const float* g1 = (const float*)d_in[3];
    const float* b1 = (const float*)d_in[4];
    const float* w2 = (const float*)d_in[5];
    // d_in[6] conv2_b: cancels exactly in batch-norm -> unused
    const float* g2 = (const float*)d_in[7];
    const float* b2 = (const float*)d_in[8];
    const float* wq = (const float*)d_in[9];
    const float* wk = (const float*)d_in[10];
    const float* wv = (const float*)d_in[11];
    const float* lw = (const float*)d_in[12];
    const float* lb = (const float*)d_in[13];

    float* ws   = (float*)d_ws;
    float* h1   = ws + OFF_H1;
    float* h2   = ws + OFF_H2;
    float* Sm   = ws + OFF_S;
    float* qqt  = ws + OFF_QQT;
    float* kkt  = ws + OFF_KKT;
    float* vpm  = ws + OFF_VP;
    float* p1a  = ws + OFF_P1;
    float* p2a  = ws + OFF_P2;
    float* bn1p = ws + OFF_BN1;
    float* bn2p = ws + OFF_BN2;

    k1_conv1<<<BSZ, 256, 0, stream>>>(x, w1, h1, p1a);
    k2_bn1<<<CEEG, 64, 0, stream>>>(p1a, g1, b1, bn1p);
    dim3 g3(BSZ/2, NTILE);
    k3_conv2<<<g3, 256, 0, stream>>>(h1, w2, bn1p, h2, p2a);
    k4_bn2<<<C2, 256, 0, stream>>>(p2a, g2, b2, bn2p);
    k5_gram<<<BSZ*3, 256, 0, stream>>>(h2, bn2p, Sm);
    k6_eig<<<BSZ*3, 256, 0, stream>>>(Sm, wq, wk, wv, qqt, kkt, vpm);
    k7_out<<<BSZ, 64, 0, stream>>>(qqt, kkt, vpm, lw, lb, (float*)d_out);
}